// Round 3
// baseline (693.782 us; speedup 1.0000x reference)
//
#include <hip/hip_runtime.h>

#define TT 256
#define BB 32
#define KK 128
#define FSMALL 1.1754943508222875e-38f   // np.finfo(float32).tiny

#define NSLOT 16                          // 8 slices x 2 halves
#define GSLOT_COUNT (BB * 2 * NSLOT * KK) // 131072 tagged 8B slots = 1 MiB

// Zero the tagged-slot array each call (graph replays must not see old tags).
__global__ void init_ws_kernel(unsigned long long* __restrict__ g) {
    size_t idx = (size_t)blockIdx.x * blockDim.x + threadIdx.x;
    g[idx] = 0ull;
}

// 256 blocks = 32 batches x 8 row-slices; 256 threads = 128 cols x 2 halves.
// Thread (s, h, j): rows 16s+8h .. +7, column j of the per-step K x K tile.
// Exchange protocol: each thread publishes its partial as {tag=step, bits}
// via 8B agent-scope relaxed atomics (coherence-point, no fences needed:
// consumers' loads bypass L1/L2 so a matching tag implies fresh data).
// Lagged-max rescaling identical to round 2 (exact algebra):
//   s_i[j] = sum_k t[k][j] u_{i-1}[k];  u_i = (s_i + eps*sumu)*exp(e_i - lmax)
//   f_i[j] = log(s_i + eps*sumu) + ref_i + e_i;  prefix_i = ref_i + log(sumu_i)
__global__ __launch_bounds__(256)
void hmm_fwd_mb(const float* __restrict__ trans,   // [T,B,K,K]
                const float* __restrict__ emis,    // [T,B,K]
                const float* __restrict__ start,   // [1,K]
                float* __restrict__ out0,          // [T,B]
                float* __restrict__ fm,            // [T,B,K]
                unsigned long long* __restrict__ gslot)
{
    const int bid = blockIdx.x;
    // slices of a batch share blockIdx % 8 -> same XCD under round-robin (perf heuristic only)
    const int b   = (bid & 7) + 8 * ((bid >> 3) & 3);
    const int s   = bid >> 5;            // row-slice 0..7
    const int tid = threadIdx.x;
    const int j   = tid & 127;
    const int h   = tid >> 7;            // 0/1: rows 16s+8h..+7
    const int wid = tid >> 6;            // wave id 0..3
    const int rowBase = 16 * s + 8 * h;

    __shared__ __align__(16) float u_buf[2][KK];   // parity double-buffer
    __shared__ float slots[2][4];                  // {mu_w0, su_w0, mu_w1, su_w1}

    const size_t tile    = (size_t)KK * KK;
    const size_t tstride = (size_t)BB * tile;
    const float* tb = trans + (size_t)b * tile + (size_t)rowBase * KK + j;

    unsigned long long* gb = gslot + (size_t)b * 2 * (NSLOT * KK);
    // slot index: par*(NSLOT*KK) + q*KK + j,  q = s*2 + h

    float A[8], Bf[8], C[8];

#define PRELOAD(BUF, t) do {                                                 \
        const float* _p = tb + (size_t)(t) * tstride;                        \
        _Pragma("unroll")                                                    \
        for (int _r = 0; _r < 8; ++_r) BUF[_r] = _p[(size_t)_r * KK];        \
    } while (0)

    PRELOAD(A, 0); PRELOAD(Bf, 1); PRELOAD(C, 2);

    float R, ll_prev = 0.f, e_cur, pe, ceps;

    // ---------------- prologue: step 0 ----------------
    {
        float e0 = emis[(size_t)b * KK + j];
        float e1 = emis[(size_t)(BB + b) * KK + j];
        float f0 = __logf(start[j] + FSMALL) + e0;
        if (h == 0) {
            float mf = f0;
            #pragma unroll
            for (int o = 32; o >= 1; o >>= 1) mf = fmaxf(mf, __shfl_xor(mf, o));
            if ((tid & 63) == 0) slots[1][2 * wid] = mf;      // temp use
        }
        __syncthreads();
        float m0 = fmaxf(slots[1][0], slots[1][2]);           // ref_0 = max f0
        R = m0;
        float u0 = __expf(f0 - m0);
        __syncthreads();
        if (h == 0) {
            u_buf[0][j] = u0;
            float mu = u0, su = u0;
            #pragma unroll
            for (int o = 32; o >= 1; o >>= 1) {
                mu = fmaxf(mu, __shfl_xor(mu, o));
                su += __shfl_xor(su, o);
            }
            if ((tid & 63) == 0) { slots[0][2*wid] = mu; slots[0][2*wid+1] = su; }
        } else if (s == 0) {
            fm[(size_t)b * KK + j] = f0;
        }
        __syncthreads();
        float maxu = fmaxf(slots[0][0], slots[0][2]);
        float sumu = slots[0][1] + slots[0][3];
        float lmax = __logf(maxu);                            // = 0 exactly
        if (s == 0 && tid == 0) {
            float pf = R + __logf(sumu);
            out0[b] = pf;
            ll_prev = pf;
        }
        R += lmax;
        pe   = __expf(e1 - lmax);
        ceps = FSMALL * sumu;
        e_cur = e1;
        // FMA with T(0) -> partials for f_1 (tag 1, parity 1)
        const float4* wp = (const float4*)&u_buf[0][rowBase];
        float4 w0 = wp[0], w1 = wp[1];
        float acc = w0.x*A[0] + w0.y*A[1] + w0.z*A[2] + w0.w*A[3]
                  + w1.x*A[4] + w1.y*A[5] + w1.z*A[6] + w1.w*A[7];
        unsigned long long pv = (1ull << 32) | __float_as_uint(acc);
        __hip_atomic_store(&gb[(size_t)(NSLOT * KK) + (s * 2 + h) * KK + j], pv,
                           __ATOMIC_RELAXED, __HIP_MEMORY_SCOPE_AGENT);
    }

#define STEP(i, CUR, NXT) do {                                               \
        PRELOAD(NXT, ((i) + 2 <= TT - 2) ? (i) + 2 : TT - 2);                \
        float e_nxt = emis[(size_t)((((i)+1 < TT) ? (i)+1 : TT-1) * BB + b)  \
                           * KK + j];                                        \
        const int par = (i) & 1;                                             \
        unsigned long long* sp = gb + (size_t)par * (NSLOT * KK) + j;        \
        float fv[16];                                                        \
        unsigned long long vv[16];                                           \
        unsigned pending = 0xFFFFu;                                          \
        while (pending) {                                                    \
            _Pragma("unroll")                                                \
            for (int q = 0; q < 16; ++q)                                     \
                if (pending & (1u << q))                                     \
                    vv[q] = __hip_atomic_load(&sp[(size_t)q * KK],           \
                              __ATOMIC_RELAXED, __HIP_MEMORY_SCOPE_AGENT);   \
            _Pragma("unroll")                                                \
            for (int q = 0; q < 16; ++q)                                     \
                if ((pending & (1u << q)) &&                                 \
                    (unsigned)(vv[q] >> 32) == (unsigned)(i)) {              \
                    fv[q] = __uint_as_float((unsigned)vv[q]);                \
                    pending &= ~(1u << q);                                   \
                }                                                            \
        }                                                                    \
        float sj = (((fv[0]+fv[1])+(fv[2]+fv[3]))                            \
                  + ((fv[4]+fv[5])+(fv[6]+fv[7])))                           \
                 + (((fv[8]+fv[9])+(fv[10]+fv[11]))                          \
                  + ((fv[12]+fv[13])+(fv[14]+fv[15])));                      \
        float sc = sj + ceps;                                                \
        float u  = sc * pe;              /* u_i, critical path ends */       \
        if (h == 0) {                                                        \
            u_buf[par][j] = u;                                               \
            float mu = u, su = u;                                            \
            _Pragma("unroll")                                                \
            for (int o = 32; o >= 1; o >>= 1) {                              \
                mu = fmaxf(mu, __shfl_xor(mu, o));                           \
                su += __shfl_xor(su, o);                                     \
            }                                                                \
            if ((tid & 63) == 0) { slots[par][2*wid] = mu;                   \
                                   slots[par][2*wid+1] = su; }               \
        } else if (s == 0) {                                                 \
            float fval = __logf(sc) + R + e_cur;   /* f_i */                 \
            fm[((size_t)(i) * BB + b) * KK + j] = fval;                      \
        }                                                                    \
        __syncthreads();                                                     \
        float maxu = fmaxf(slots[par][0], slots[par][2]);                    \
        float sumu = slots[par][1] + slots[par][3];                          \
        float lmax = __logf(maxu);                                           \
        if (s == 0 && tid == 0) {                                            \
            float pf = R + __logf(sumu);           /* prefix_i */            \
            out0[(size_t)(i) * BB + b] = pf - ll_prev;                       \
            ll_prev = pf;                                                    \
        }                                                                    \
        R += lmax;                                                           \
        pe   = __expf(e_nxt - lmax);                                         \
        ceps = FSMALL * sumu;                                                \
        e_cur = e_nxt;                                                       \
        if ((i) < TT - 1) {                                                  \
            const float4* wp = (const float4*)&u_buf[par][rowBase];          \
            float4 w0 = wp[0], w1 = wp[1];                                   \
            float acc = w0.x*CUR[0] + w0.y*CUR[1] + w0.z*CUR[2] + w0.w*CUR[3]\
                      + w1.x*CUR[4] + w1.y*CUR[5] + w1.z*CUR[6] + w1.w*CUR[7];\
            unsigned long long pv =                                          \
                ((unsigned long long)(unsigned)((i)+1) << 32)                \
                | __float_as_uint(acc);                                      \
            __hip_atomic_store(&gb[(size_t)(((i)+1)&1)*(NSLOT*KK)            \
                                   + (s*2+h)*KK + j], pv,                    \
                               __ATOMIC_RELAXED, __HIP_MEMORY_SCOPE_AGENT);  \
        }                                                                    \
    } while (0)

    // -------- main recursion: iters 1..255, 3-deep prefetch rotation ------
    #pragma unroll 1
    for (int m = 0; m < 85; ++m) {
        const int i0 = 3 * m + 1;
        STEP(i0,     Bf, A);
        STEP(i0 + 1, C,  Bf);
        STEP(i0 + 2, A,  C);
    }
    // out0[255] emitted inside STEP(255); nothing else to do.

#undef PRELOAD
#undef STEP
}

extern "C" void kernel_launch(void* const* d_in, const int* in_sizes, int n_in,
                              void* d_out, int out_size, void* d_ws, size_t ws_size,
                              hipStream_t stream) {
    // d_in order: sequences (unused), transitions, emissions, start_transitions
    const float* trans = (const float*)d_in[1];
    const float* emis  = (const float*)d_in[2];
    const float* start = (const float*)d_in[3];
    float* out0 = (float*)d_out;                     // [T,B]
    float* fm   = (float*)d_out + (size_t)TT * BB;   // [T,B,K]
    unsigned long long* gslot = (unsigned long long*)d_ws;  // 1 MiB of tagged slots

    hipLaunchKernelGGL(init_ws_kernel, dim3(GSLOT_COUNT / 256), dim3(256), 0, stream,
                       gslot);
    hipLaunchKernelGGL(hmm_fwd_mb, dim3(256), dim3(256), 0, stream,
                       trans, emis, start, out0, fm, gslot);
}

// Round 4
// 329.580 us; speedup vs baseline: 2.1050x; 2.1050x over previous
//
#include <hip/hip_runtime.h>

#define TT 256
#define BB 32
#define KK 128
#define FSMALL 1.1754943508222875e-38f   // np.finfo(float32).tiny

// Raw barrier: drain own LDS ops (visibility to other waves), then s_barrier.
// Crucially does NOT drain vmcnt -> global prefetches stay in flight across
// barriers (unlike __syncthreads, which emits s_waitcnt vmcnt(0)).
#define BARRIER() asm volatile("s_waitcnt lgkmcnt(0)\n\ts_barrier" ::: "memory")

// One block per batch. 1024 threads = 8 row-groups x 128 cols.
// Thread (g,j): rows 16g..16g+15, column j of the per-step K x K tile.
// Lagged-max rescaling (exact algebra, same as the 363us round-2 kernel):
//   u_i[j] = exp(f_i[j] - R_i),  R_i = R_{i-1} + log(max_j u_{i-1})
//   sc_i   = sum_k t_i[k][j] u_{i-1}[k] + eps*sumu_{i-1}
//   u_i    = sc_i * exp(e_i - lmax_{i-1});  f_i = log(sc_i) + R_{i-1} + e_i
//   prefix_i = R_i + log(sumu_i)
// Phases per step: P1 (fin waves 0-1 finalize) | bar | P2 (all: FMA + shadow
// work: shuffles, fm/out0 stores, prefetch trans+emis) | bar.
// All LDS buffers single-buffered: every RAW/WAR pair is adjacent-barrier
// separated (partial: W@P2(i) R@P1(i+1) W@P2(i+1); w: W@P1 R@P2 W@P1';
// slots: W@P2 R@P1' W@P2').
__global__ __launch_bounds__(1024, 1)
void hmm_fwd(const float* __restrict__ trans,   // [T,B,K,K]
             const float* __restrict__ emis,    // [T,B,K]
             const float* __restrict__ start,   // [1,K]
             float* __restrict__ out0,          // [T,B]
             float* __restrict__ fm)            // [T,B,K]
{
    const int b   = blockIdx.x;
    const int tid = threadIdx.x;
    const int g   = tid >> 7;       // row group 0..7
    const int j   = tid & 127;      // column 0..127
    const int wid = tid >> 6;       // wave id (fin uses 0/1)
    const bool fin = (tid < KK);    // waves 0-1 run the finalize

    __shared__ __align__(16) float w_lds[KK];
    __shared__ __align__(16) float partial[8][KK];
    __shared__ __align__(16) float slots[4];    // {mu_w0, su_w0, mu_w1, su_w1}
    __shared__ float xs[2];

    const size_t tile    = (size_t)KK * KK;
    const size_t tstride = (size_t)BB * tile;
    const float* tb = trans + (size_t)b * tile + (size_t)(16 * g) * KK + j;

    float A[16], Bf[16], C[16];
    float eA = 0.f, eB = 0.f, eC = 0.f;
    float R = 0.f, Rold = 0.f, ll_prev = 0.f, pe = 0.f, ceps = 0.f;
    float u = 0.f, sc = 0.f, sumu_sv = 0.f;

#define PRELOAD(BUF, t) do {                                                 \
        const float* _p = tb + (size_t)(t) * tstride;                        \
        _Pragma("unroll")                                                    \
        for (int _r = 0; _r < 16; ++_r) BUF[_r] = _p[(size_t)_r * KK];       \
    } while (0)

    PRELOAD(A, 0); PRELOAD(Bf, 1); PRELOAD(C, 2);

    // ---------------- prologue: step 0 ----------------
    float f0 = 0.f;
    if (fin) {
        float e0 = emis[(size_t)b * KK + j];
        f0 = __logf(start[j] + FSMALL) + e0;
        fm[(size_t)b * KK + j] = f0;
        float mf = f0;
        #pragma unroll
        for (int o = 32; o >= 1; o >>= 1) mf = fmaxf(mf, __shfl_xor(mf, o));
        if ((tid & 63) == 0) xs[wid] = mf;
    }
    BARRIER();
    if (fin) {
        float m0 = fmaxf(xs[0], xs[1]);    // R_0 = max f0 (exact)
        R = m0;
        u = __expf(f0 - m0);
        w_lds[j] = u;
    }
    BARRIER();
    // P2(0): FMA with t(0)=A -> partials for step 1; shadow work for step 0.
    {
        const float4* wp = (const float4*)&w_lds[16 * g];
        float4 w0 = wp[0], w1 = wp[1], w2 = wp[2], w3 = wp[3];
        float a0 = w0.x*A[0]  + w0.y*A[1]  + w0.z*A[2]  + w0.w*A[3];
        float a1 = w1.x*A[4]  + w1.y*A[5]  + w1.z*A[6]  + w1.w*A[7];
        float a2 = w2.x*A[8]  + w2.y*A[9]  + w2.z*A[10] + w2.w*A[11];
        float a3 = w3.x*A[12] + w3.y*A[13] + w3.z*A[14] + w3.w*A[15];
        partial[g][j] = (a0 + a1) + (a2 + a3);
    }
    PRELOAD(A, 3);                          // A consumed; reload for P2(3)
    if (fin) {
        float mu = u, su = u;
        #pragma unroll
        for (int o = 32; o >= 1; o >>= 1) {
            mu = fmaxf(mu, __shfl_xor(mu, o));
            su += __shfl_xor(su, o);
        }
        if ((tid & 63) == 0) { slots[2*wid] = mu; slots[2*wid+1] = su; }
        eA = emis[((size_t)1 * BB + b) * KK + j];   // e_1
        eB = emis[((size_t)2 * BB + b) * KK + j];   // e_2
        eC = emis[((size_t)3 * BB + b) * KK + j];   // e_3
    }
    BARRIER();

#define STEP(i, BUF, E) do {                                                 \
        /* ---- P1: finalize u_i (fin waves only) ---- */                    \
        if (fin) {                                                           \
            float _s0 = slots[0], _s1 = slots[1];                            \
            float _s2 = slots[2], _s3 = slots[3];                            \
            float _p0 = partial[0][j], _p1 = partial[1][j];                  \
            float _p2 = partial[2][j], _p3 = partial[3][j];                  \
            float _p4 = partial[4][j], _p5 = partial[5][j];                  \
            float _p6 = partial[6][j], _p7 = partial[7][j];                  \
            float _maxu = fmaxf(_s0, _s2);                                   \
            sumu_sv = _s1 + _s3;                                             \
            float _lmax = __logf(_maxu);                                     \
            Rold = R; R += _lmax;                                            \
            pe   = __expf(E - _lmax);                                        \
            ceps = FSMALL * sumu_sv;                                         \
            sc = (((_p0+_p1)+(_p2+_p3)) + ((_p4+_p5)+(_p6+_p7))) + ceps;     \
            u  = sc * pe;                                                    \
            w_lds[j] = u;                                                    \
        }                                                                    \
        BARRIER();                                                           \
        /* ---- P2: GEMV partials for step i+1; shadow work ---- */          \
        {                                                                    \
            const float4* _wp = (const float4*)&w_lds[16 * g];               \
            float4 _w0 = _wp[0], _w1 = _wp[1], _w2 = _wp[2], _w3 = _wp[3];   \
            float _a0 = _w0.x*BUF[0]  + _w0.y*BUF[1]                         \
                      + _w0.z*BUF[2]  + _w0.w*BUF[3];                        \
            float _a1 = _w1.x*BUF[4]  + _w1.y*BUF[5]                         \
                      + _w1.z*BUF[6]  + _w1.w*BUF[7];                        \
            float _a2 = _w2.x*BUF[8]  + _w2.y*BUF[9]                         \
                      + _w2.z*BUF[10] + _w2.w*BUF[11];                       \
            float _a3 = _w3.x*BUF[12] + _w3.y*BUF[13]                        \
                      + _w3.z*BUF[14] + _w3.w*BUF[15];                       \
            partial[g][j] = (_a0 + _a1) + (_a2 + _a3);                       \
        }                                                                    \
        PRELOAD(BUF, ((i) + 3 <= TT - 1) ? (i) + 3 : TT - 1);                \
        if (fin) {                                                           \
            float _mu = u, _su = u;                                          \
            _Pragma("unroll")                                                \
            for (int _o = 32; _o >= 1; _o >>= 1) {                           \
                _mu = fmaxf(_mu, __shfl_xor(_mu, _o));                       \
                _su += __shfl_xor(_su, _o);                                  \
            }                                                                \
            if ((tid & 63) == 0) { slots[2*wid] = _mu; slots[2*wid+1] = _su; }\
            float _fv = __logf(sc) + Rold + E;                               \
            fm[((size_t)(i) * BB + b) * KK + j] = _fv;                       \
            if (tid == 0) {                                                  \
                float _pf = Rold + __logf(sumu_sv);                          \
                out0[(size_t)((i) - 1) * BB + b] = _pf - ll_prev;            \
                ll_prev = _pf;                                               \
            }                                                                \
            E = emis[(size_t)(((((i) + 3 <= TT - 1) ? (i) + 3 : TT - 1))     \
                              * BB + b) * KK + j];                           \
        }                                                                    \
        BARRIER();                                                           \
    } while (0)

    // -------- main recursion: steps 1..255 (P2(i) consumes t(i)) ----------
    #pragma unroll 1
    for (int m = 0; m < 85; ++m) {
        const int i0 = 3 * m + 1;
        STEP(i0,     Bf, eA);
        STEP(i0 + 1, C,  eB);
        STEP(i0 + 2, A,  eC);
    }

    // -------- epilogue: prefix increment for step 255 ----------------------
    if (tid == 0) {
        float su = slots[1] + slots[3];
        float pf = R + __logf(su);      // R = R_255 after STEP(255)'s P1
        out0[(size_t)(TT - 1) * BB + b] = pf - ll_prev;
    }

#undef PRELOAD
#undef STEP
}

extern "C" void kernel_launch(void* const* d_in, const int* in_sizes, int n_in,
                              void* d_out, int out_size, void* d_ws, size_t ws_size,
                              hipStream_t stream) {
    // d_in order: sequences (unused), transitions, emissions, start_transitions
    const float* trans = (const float*)d_in[1];
    const float* emis  = (const float*)d_in[2];
    const float* start = (const float*)d_in[3];
    float* out0 = (float*)d_out;                     // [T,B]
    float* fm   = (float*)d_out + (size_t)TT * BB;   // [T,B,K]
    hipLaunchKernelGGL(hmm_fwd, dim3(BB), dim3(1024), 0, stream,
                       trans, emis, start, out0, fm);
}